// Round 8
// baseline (403.881 us; speedup 1.0000x reference)
//
#include <hip/hip_runtime.h>

// Problem constants: D=512, H=8 (hd=64), DFF=2048, NE=64, ND=64, B=16
// Identities exploited:
//  - dc cross-attention has softmax over 1 key -> t[j,b] = Wo(Wv f_n[j,b]+bv)+bo
//  - G_fj[j,i,b] = dec[i,b] + t[j,b]  (rank-decomposed; never materialized)
//  - LN(G_fj) linearity: K/V projections & pooling energy decompose into
//    per-i and per-j 1024-row GEMMs + scalar stats m[j,i,b], r[j,i,b].
// R2: bf16 MFMA GEMMs. R4: all-bf16 (L2-resident). R5-R7: pool/self/ec ->
// coalesced + MFMA flash blocks. R8: GEMM drops LDS staging entirely --
// fragments load global->VGPR (slabs are L1/L2-resident), zero barriers;
// LN(enc)+stats(dec) fused into one dispatch.

typedef __bf16 bf16_t;
typedef bf16_t bf16x8 __attribute__((ext_vector_type(8)));
typedef float f32x4 __attribute__((ext_vector_type(4)));
typedef unsigned short u16x4 __attribute__((ext_vector_type(4)));
typedef unsigned short u16x8 __attribute__((ext_vector_type(8)));

__device__ inline unsigned short f2bf(float f) {
  unsigned int u = __float_as_uint(f);
  u += 0x7fffu + ((u >> 16) & 1u);  // RNE
  return (unsigned short)(u >> 16);
}
__device__ inline float bf2f(unsigned short u) {
  return __uint_as_float(((unsigned int)u) << 16);
}

__device__ inline float wsum(float v) {
#pragma unroll
  for (int o = 1; o < 64; o <<= 1) v += __shfl_xor(v, o);
  return v;
}
__device__ inline float wmax(float v) {
#pragma unroll
  for (int o = 1; o < 64; o <<= 1) v = fmaxf(v, __shfl_xor(v, o));
  return v;
}

// ---------------- weight cast fp32 -> bf16 (optional per-K colscale) --------
struct CastJob {
  const float* src;
  unsigned short* dst;
  int n;
  const float* cs;  // per-(i & 511) scale or null
};
struct CastBatch {
  CastJob j[15];
};

__global__ __launch_bounds__(256) void cast_w(CastBatch cb) {
  const CastJob jb = cb.j[blockIdx.y];
  const int stride = 32 * 256 * 4;
  for (int i = (blockIdx.x * 256 + threadIdx.x) * 4; i < jb.n; i += stride) {
    float4 v = *(const float4*)(jb.src + i);
    if (jb.cs) {
      int k = i & 511;
      v.x *= jb.cs[k];
      v.y *= jb.cs[k + 1];
      v.z *= jb.cs[k + 2];
      v.w *= jb.cs[k + 3];
    }
    u16x4 o = {f2bf(v.x), f2bf(v.y), f2bf(v.z), f2bf(v.w)};
    *(u16x4*)(jb.dst + i) = o;
  }
}

// ---------------- LayerNorm over last dim (512) -> bf16 out -----------------
__device__ inline void ln_body(const float* __restrict__ x,
                               const float* __restrict__ g,
                               const float* __restrict__ be,
                               unsigned short* __restrict__ y, int t) {
  float v0 = x[t], v1 = x[t + 256];
  float s = wsum(v0 + v1);
  float s2 = wsum(v0 * v0 + v1 * v1);
  __shared__ float sh[8];
  int w = t >> 6, lane = t & 63;
  if (lane == 0) { sh[w] = s; sh[4 + w] = s2; }
  __syncthreads();
  s = sh[0] + sh[1] + sh[2] + sh[3];
  s2 = sh[4] + sh[5] + sh[6] + sh[7];
  float mean = s * (1.f / 512.f);
  float var = s2 * (1.f / 512.f) - mean * mean;
  float r = rsqrtf(var + 1e-5f);
  y[t] = f2bf((v0 - mean) * r * g[t] + be[t]);
  y[t + 256] = f2bf((v1 - mean) * r * g[t + 256] + be[t + 256]);
}

__device__ inline void stats_body(const float* __restrict__ x,
                                  float* __restrict__ m, float* __restrict__ q2,
                                  unsigned short* __restrict__ xb, int t,
                                  int row) {
  float v0 = x[t], v1 = x[t + 256];
  if (xb) {
    xb[t] = f2bf(v0);
    xb[t + 256] = f2bf(v1);
  }
  float s = wsum(v0 + v1);
  float s2 = wsum(v0 * v0 + v1 * v1);
  __shared__ float sh2[8];
  int w = t >> 6, lane = t & 63;
  if (lane == 0) { sh2[w] = s; sh2[4 + w] = s2; }
  __syncthreads();
  if (t == 0) {
    s = sh2[0] + sh2[1] + sh2[2] + sh2[3];
    s2 = sh2[4] + sh2[5] + sh2[6] + sh2[7];
    m[row] = s * (1.f / 512.f);
    q2[row] = s2 * (1.f / 512.f);
  }
}

// fused: rows<1024 -> LN(enc)->f_n_b; rows>=1024 -> stats(dec)+cast->dec_b
__global__ __launch_bounds__(256) void ln_stats_kernel(
    const float* __restrict__ enc, const float* __restrict__ g,
    const float* __restrict__ be, unsigned short* __restrict__ f_n,
    const float* __restrict__ dec, float* __restrict__ md,
    float* __restrict__ q2d, unsigned short* __restrict__ dec_b) {
  int row = blockIdx.x;
  if (row < 1024) {
    ln_body(enc + (size_t)row * 512, g, be, f_n + (size_t)row * 512,
            threadIdx.x);
  } else {
    row -= 1024;
    stats_body(dec + (size_t)row * 512, md, q2d, dec_b + (size_t)row * 512,
               threadIdx.x, row);
  }
}

__global__ __launch_bounds__(256) void stats_kernel(
    const float* __restrict__ X, float* __restrict__ m, float* __restrict__ q2,
    unsigned short* __restrict__ Xb) {
  int row = blockIdx.x;
  stats_body(X + (size_t)row * 512, m, q2, Xb ? Xb + (size_t)row * 512 : nullptr,
             threadIdx.x, row);
}

__global__ __launch_bounds__(256) void ln2_kernel(
    const float* __restrict__ X0, const float* __restrict__ g0,
    const float* __restrict__ b0, unsigned short* __restrict__ Y0,
    const float* __restrict__ X1, const float* __restrict__ g1,
    const float* __restrict__ b1, unsigned short* __restrict__ Y1) {
  int row = blockIdx.x;
  if (row < 1024) {
    ln_body(X0 + (size_t)row * 512, g0, b0, Y0 + (size_t)row * 512, threadIdx.x);
  } else {
    row -= 1024;
    ln_body(X1 + (size_t)row * 512, g1, b1, Y1 + (size_t)row * 512, threadIdx.x);
  }
}

// ---------------- u/c vectors: one wave per output row ----------------------
__global__ __launch_bounds__(256) void uvec_kernel(
    const float* __restrict__ Wk, const float* __restrict__ Wv,
    const float* __restrict__ bk, const float* __restrict__ bv,
    const float* __restrict__ g, const float* __restrict__ beta,
    float* __restrict__ u_k, float* __restrict__ u_v,
    float* __restrict__ c_k, float* __restrict__ c_v) {
  int n = blockIdx.x * 4 + (threadIdx.x >> 6);
  int lane = threadIdx.x & 63;
  const float* wk = Wk + (size_t)n * 512;
  const float* wv = Wv + (size_t)n * 512;
  float uk = 0.f, uv = 0.f, ck = 0.f, cv = 0.f;
#pragma unroll
  for (int k0 = 0; k0 < 512; k0 += 64) {
    int k = k0 + lane;
    float a = wk[k], b2 = wv[k], gg = g[k], bb = beta[k];
    uk += a * gg;
    ck += a * bb;
    uv += b2 * gg;
    cv += b2 * bb;
  }
  uk = wsum(uk);
  uv = wsum(uv);
  ck = wsum(ck);
  cv = wsum(cv);
  if (lane == 0) {
    u_k[n] = uk;
    u_v[n] = uv;
    c_k[n] = ck + bk[n];
    c_v[n] = cv + bv[n];
  }
}

// ---------------- per-(j,i,b) LN stats, output b-major: [b][j][i] -----------
__global__ __launch_bounds__(256) void mr_kernel(
    const float* __restrict__ dec, const float* __restrict__ t,
    const float* __restrict__ md, const float* __restrict__ q2d,
    const float* __restrict__ mt, const float* __restrict__ q2t,
    float* __restrict__ mArr, float* __restrict__ rArr) {
  int wid = blockIdx.x * 4 + (threadIdx.x >> 6);
  int lane = threadIdx.x & 63;
  int b = wid & 15;
  int i = (wid >> 4) & 63;
  int j = wid >> 10;
  const float* dr = dec + (size_t)(i * 16 + b) * 512;
  const float* tr = t + (size_t)(j * 16 + b) * 512;
  float s = 0.f;
#pragma unroll
  for (int k = 0; k < 8; ++k) s += dr[lane + 64 * k] * tr[lane + 64 * k];
  s = wsum(s);
  if (lane == 0) {
    float mean = md[i * 16 + b] + mt[j * 16 + b];
    float msq = q2d[i * 16 + b] + q2t[j * 16 + b] + 2.f * s * (1.f / 512.f);
    float var = msq - mean * mean;
    int idx = b * 4096 + j * 64 + i;
    mArr[idx] = mean;
    rArr[idx] = rsqrtf(var + 1e-5f);
  }
}

// ---------------- ec cross-attention: MFMA flash block per (b,h) ------------
__global__ __launch_bounds__(256) void ec_attn(
    const unsigned short* __restrict__ Qe, const unsigned short* __restrict__ Kd,
    const unsigned short* __restrict__ Kt, const unsigned short* __restrict__ Vd,
    const unsigned short* __restrict__ Vt, const float* __restrict__ u_k,
    const float* __restrict__ u_v, const float* __restrict__ c_k,
    const float* __restrict__ c_v, const float* __restrict__ mArr,
    const float* __restrict__ rArr, unsigned short* __restrict__ O) {
  int h = blockIdx.x & 7;
  int b = blockIdx.x >> 3;
  __shared__ unsigned short Qs[64][72];
  __shared__ unsigned short Ks[64][72];
  __shared__ unsigned short VdT[64][72];
  __shared__ unsigned short Ps[64][72];
  __shared__ float ms[64][66];
  __shared__ float rs[64][66];
  __shared__ float stp[64][4], sup[64][4], scp[64][4];
  __shared__ float stv[64], suv[64], scv[64], swv[64], swmv[64];
  int t = threadIdx.x;
  {
    int row = t >> 2;
    int qt = t & 3;
    int cb = qt * 16;
    size_t base = (size_t)(row * 16 + b) * 512 + h * 64 + cb;
    u16x8 q0 = *(const u16x8*)(Qe + base);
    u16x8 q1 = *(const u16x8*)(Qe + base + 8);
    u16x8 k0 = *(const u16x8*)(Kd + base);
    u16x8 k1 = *(const u16x8*)(Kd + base + 8);
    u16x8 kt0 = *(const u16x8*)(Kt + base);
    u16x8 kt1 = *(const u16x8*)(Kt + base + 8);
    u16x8 v0 = *(const u16x8*)(Vd + base);
    u16x8 v1 = *(const u16x8*)(Vd + base + 8);
    *(u16x8*)&Qs[row][cb] = q0;
    *(u16x8*)&Qs[row][cb + 8] = q1;
    *(u16x8*)&Ks[row][cb] = k0;
    *(u16x8*)&Ks[row][cb + 8] = k1;
#pragma unroll
    for (int jj = 0; jj < 8; ++jj) VdT[cb + jj][row] = v0[jj];
#pragma unroll
    for (int jj = 0; jj < 8; ++jj) VdT[cb + 8 + jj][row] = v1[jj];
    float st_ = 0.f, su_ = 0.f, sc_ = 0.f;
#pragma unroll
    for (int jj = 0; jj < 8; ++jj) {
      float qa = bf2f(q0[jj]), qb = bf2f(q1[jj]);
      st_ += qa * bf2f(kt0[jj]) + qb * bf2f(kt1[jj]);
      su_ += qa * u_k[h * 64 + cb + jj] + qb * u_k[h * 64 + cb + 8 + jj];
      sc_ += qa * c_k[h * 64 + cb + jj] + qb * c_k[h * 64 + cb + 8 + jj];
    }
    stp[row][qt] = st_;
    sup[row][qt] = su_;
    scp[row][qt] = sc_;
  }
#pragma unroll
  for (int k = 0; k < 16; ++k) {
    int idx = t + k * 256;
    ms[idx >> 6][idx & 63] = mArr[(size_t)b * 4096 + idx];
    rs[idx >> 6][idx & 63] = rArr[(size_t)b * 4096 + idx];
  }
  __syncthreads();
  if (t < 64) {
    stv[t] = stp[t][0] + stp[t][1] + stp[t][2] + stp[t][3];
    suv[t] = sup[t][0] + sup[t][1] + sup[t][2] + sup[t][3];
    scv[t] = scp[t][0] + scp[t][1] + scp[t][2] + scp[t][3];
  }
  __syncthreads();
  int wave = t >> 6, lane = t & 63;
  int fr = lane & 15, fg = lane >> 4;
  f32x4 sacc[4] = {};
  bf16x8 aq0 = *(const bf16x8*)&Qs[wave * 16 + fr][fg * 8];
  bf16x8 aq1 = *(const bf16x8*)&Qs[wave * 16 + fr][32 + fg * 8];
#pragma unroll
  for (int nt = 0; nt < 4; ++nt) {
    bf16x8 b0 = *(const bf16x8*)&Ks[nt * 16 + fr][fg * 8];
    bf16x8 b1 = *(const bf16x8*)&Ks[nt * 16 + fr][32 + fg * 8];
    sacc[nt] = __builtin_amdgcn_mfma_f32_16x16x32_bf16(aq0, b0, sacc[nt], 0, 0, 0);
    sacc[nt] = __builtin_amdgcn_mfma_f32_16x16x32_bf16(aq1, b1, sacc[nt], 0, 0, 0);
  }
#pragma unroll
  for (int r = 0; r < 4; ++r) {
    int j = wave * 16 + fg * 4 + r;
    float stj = stv[j], suj = suv[j], scj = scv[j];
    float a0, a1, a2, a3;
    {
      int i0 = fr, i1 = 16 + fr, i2 = 32 + fr, i3 = 48 + fr;
      a0 = rs[j][i0] * (sacc[0][r] + stj - ms[j][i0] * suj) + scj;
      a1 = rs[j][i1] * (sacc[1][r] + stj - ms[j][i1] * suj) + scj;
      a2 = rs[j][i2] * (sacc[2][r] + stj - ms[j][i2] * suj) + scj;
      a3 = rs[j][i3] * (sacc[3][r] + stj - ms[j][i3] * suj) + scj;
    }
    float mx = fmaxf(fmaxf(a0, a1), fmaxf(a2, a3));
#pragma unroll
    for (int o = 1; o < 16; o <<= 1) mx = fmaxf(mx, __shfl_xor(mx, o));
    a0 = __expf(a0 - mx);
    a1 = __expf(a1 - mx);
    a2 = __expf(a2 - mx);
    a3 = __expf(a3 - mx);
    float se = a0 + a1 + a2 + a3;
#pragma unroll
    for (int o = 1; o < 16; o <<= 1) se += __shfl_xor(se, o);
    float inv = 1.f / se;
    float w0 = a0 * inv * rs[j][fr];
    float w1 = a1 * inv * rs[j][16 + fr];
    float w2 = a2 * inv * rs[j][32 + fr];
    float w3 = a3 * inv * rs[j][48 + fr];
    float sw = w0 + w1 + w2 + w3;
    float swm = w0 * ms[j][fr] + w1 * ms[j][16 + fr] + w2 * ms[j][32 + fr] +
                w3 * ms[j][48 + fr];
#pragma unroll
    for (int o = 1; o < 16; o <<= 1) {
      sw += __shfl_xor(sw, o);
      swm += __shfl_xor(swm, o);
    }
    Ps[j][fr] = f2bf(w0);
    Ps[j][16 + fr] = f2bf(w1);
    Ps[j][32 + fr] = f2bf(w2);
    Ps[j][48 + fr] = f2bf(w3);
    if (fr == 0) {
      swv[j] = sw;
      swmv[j] = swm;
    }
  }
  f32x4 oc[4] = {};
  bf16x8 ap0 = *(const bf16x8*)&Ps[wave * 16 + fr][fg * 8];
  bf16x8 ap1 = *(const bf16x8*)&Ps[wave * 16 + fr][32 + fg * 8];
#pragma unroll
  for (int nt = 0; nt < 4; ++nt) {
    bf16x8 b0 = *(const bf16x8*)&VdT[nt * 16 + fr][fg * 8];
    bf16x8 b1 = *(const bf16x8*)&VdT[nt * 16 + fr][32 + fg * 8];
    oc[nt] = __builtin_amdgcn_mfma_f32_16x16x32_bf16(ap0, b0, oc[nt], 0, 0, 0);
    oc[nt] = __builtin_amdgcn_mfma_f32_16x16x32_bf16(ap1, b1, oc[nt], 0, 0, 0);
  }
#pragma unroll
  for (int nt = 0; nt < 4; ++nt) {
    int d = nt * 16 + fr;
    float uvd = u_v[h * 64 + d];
    float cvd = c_v[h * 64 + d];
#pragma unroll
    for (int r = 0; r < 4; ++r) {
      int j = wave * 16 + fg * 4 + r;
      size_t gidx = (size_t)(j * 16 + b) * 512 + h * 64 + d;
      float o = oc[nt][r] + swv[j] * bf2f(Vt[gidx]) - swmv[j] * uvd + cvd;
      O[gidx] = f2bf(o);
    }
  }
}

// ---------------- attention pooling: coalesced, wave-per-16j ----------------
__global__ __launch_bounds__(256) void pool_kernel(
    const float* __restrict__ Ed, const float* __restrict__ Et,
    const float* __restrict__ pv, const float* __restrict__ dec,
    const unsigned short* __restrict__ tbf, float* __restrict__ dec1) {
  int i = blockIdx.x;
  int b = blockIdx.y;
  int t = threadIdx.x;
  int wave = t >> 6, lane = t & 63;
  float edv[8], pvv[8];
  const float* ed = Ed + (size_t)(i * 16 + b) * 512;
#pragma unroll
  for (int c = 0; c < 8; ++c) {
    edv[c] = ed[c * 64 + lane];
    pvv[c] = pv[c * 64 + lane];
  }
  __shared__ float esh[64];
  __shared__ float wsh[64];
#pragma unroll 1
  for (int jl = 0; jl < 16; ++jl) {
    int j = wave * 16 + jl;
    const float* et = Et + (size_t)(j * 16 + b) * 512;
    float s = 0.f;
#pragma unroll
    for (int c = 0; c < 8; ++c) {
      float x = edv[c] + et[c * 64 + lane];
      float e2 = __expf(2.f * x);
      float th = 1.f - 2.f * __builtin_amdgcn_rcpf(e2 + 1.f);  // tanh
      s += th * pvv[c];
    }
    s = wsum(s);
    if (lane == 0) esh[j] = s;
  }
  __syncthreads();
  if (t < 64) {
    float e = esh[t];
    float mx = wmax(e);
    float ex = __expf(e - mx);
    float se = wsum(ex);
    wsh[t] = ex / se;
  }
  __syncthreads();
  size_t rowib = (size_t)(i * 16 + b) * 512;
  int d2 = t * 2;
  float2 dv = *(const float2*)(dec + rowib + d2);
  float acc0 = dv.x, acc1 = dv.y;
#pragma unroll 8
  for (int j2 = 0; j2 < 64; ++j2) {
    const unsigned short* tp = tbf + (size_t)(j2 * 16 + b) * 512 + d2;
    float w = wsh[j2];
    acc0 += w * bf2f(tp[0]);
    acc1 += w * bf2f(tp[1]);
  }
  float2 ov = {acc0, acc1};
  *(float2*)(dec1 + rowib + d2) = ov;
}

// ---------------- MFMA self-attention: one block per (b,h) ------------------
__global__ __launch_bounds__(256) void self_attn(
    const unsigned short* __restrict__ QKVe, unsigned short* __restrict__ Oe,
    const unsigned short* __restrict__ QKVd, unsigned short* __restrict__ Od) {
  const unsigned short* QKV = blockIdx.y ? QKVd : QKVe;
  unsigned short* O = blockIdx.y ? Od : Oe;
  int h = blockIdx.x & 7;
  int b = blockIdx.x >> 3;
  __shared__ unsigned short Qs[64][72];
  __shared__ unsigned short Ksh[64][72];
  __shared__ unsigned short VT[64][72];
  __shared__ unsigned short Ps[64][72];
  int t = threadIdx.x;
  {
    int row = t >> 2;
    int cb = (t & 3) * 16;
    const unsigned short* src =
        QKV + (size_t)(row * 16 + b) * 1536 + h * 64 + cb;
    u16x8 q0 = *(const u16x8*)(src);
    u16x8 q1 = *(const u16x8*)(src + 8);
    u16x8 k0 = *(const u16x8*)(src + 512);
    u16x8 k1 = *(const u16x8*)(src + 520);
    u16x8 v0 = *(const u16x8*)(src + 1024);
    u16x8 v1 = *(const u16x8*)(src + 1032);
    *(u16x8*)&Qs[row][cb] = q0;
    *(u16x8*)&Qs[row][cb + 8] = q1;
    *(u16x8*)&Ksh[row][cb] = k0;
    *(u16x8*)&Ksh[row][cb + 8] = k1;
#pragma unroll
    for (int jj = 0; jj < 8; ++jj) VT[cb + jj][row] = v0[jj];
#pragma unroll
    for (int jj = 0; jj < 8; ++jj) VT[cb + 8 + jj][row] = v1[jj];
  }
  __syncthreads();
  int wave = t >> 6, lane = t & 63;
  int fr = lane & 15, fg = lane >> 4;
  f32x4 sc[4] = {};
  bf16x8 aq0 = *(const bf16x8*)&Qs[wave * 16 + fr][fg * 8];
  bf16x8 aq1 = *(const bf16x8*)&Qs[wave * 16 + fr][32 + fg * 8];
#pragma unroll
  for (int nt = 0; nt < 4; ++nt) {
    bf16x8 b0 = *(const bf16x8*)&Ksh[nt * 16 + fr][fg * 8];
    bf16x8 b1 = *(const bf16x8*)&Ksh[nt * 16 + fr][32 + fg * 8];
    sc[nt] = __builtin_amdgcn_mfma_f32_16x16x32_bf16(aq0, b0, sc[nt], 0, 0, 0);
    sc[nt] = __builtin_amdgcn_mfma_f32_16x16x32_bf16(aq1, b1, sc[nt], 0, 0, 0);
  }
#pragma unroll
  for (int r = 0; r < 4; ++r) {
    float a0 = sc[0][r] * 0.125f, a1 = sc[1][r] * 0.125f;
    float a2 = sc[2][r] * 0.125f, a3 = sc[3][r] * 0.125f;
    float mx = fmaxf(fmaxf(a0, a1), fmaxf(a2, a3));
#pragma unroll
    for (int o = 1; o < 16; o <<= 1) mx = fmaxf(mx, __shfl_xor(mx, o));
    a0 = __expf(a0 - mx);
    a1 = __expf(a1 - mx);
    a2 = __expf(a2 - mx);
    a3 = __expf(a3 - mx);
    float se = a0 + a1 + a2 + a3;
#pragma unroll
    for (int o = 1; o < 16; o <<= 1) se += __shfl_xor(se, o);
    float inv = 1.f / se;
    int prow = wave * 16 + fg * 4 + r;
    Ps[prow][0 + fr] = f2bf(a0 * inv);
    Ps[prow][16 + fr] = f2bf(a1 * inv);
    Ps[prow][32 + fr] = f2bf(a2 * inv);
    Ps[prow][48 + fr] = f2bf(a3 * inv);
  }
  f32x4 oc[4] = {};
  bf16x8 ap0 = *(const bf16x8*)&Ps[wave * 16 + fr][fg * 8];
  bf16x8 ap1 = *(const bf16x8*)&Ps[wave * 16 + fr][32 + fg * 8];
#pragma unroll
  for (int nt = 0; nt < 4; ++nt) {
    bf16x8 b0 = *(const bf16x8*)&VT[nt * 16 + fr][fg * 8];
    bf16x8 b1 = *(const bf16x8*)&VT[nt * 16 + fr][32 + fg * 8];
    oc[nt] = __builtin_amdgcn_mfma_f32_16x16x32_bf16(ap0, b0, oc[nt], 0, 0, 0);
    oc[nt] = __builtin_amdgcn_mfma_f32_16x16x32_bf16(ap1, b1, oc[nt], 0, 0, 0);
  }
#pragma unroll
  for (int nt = 0; nt < 4; ++nt) {
#pragma unroll
    for (int r = 0; r < 4; ++r) {
      int q = wave * 16 + fg * 4 + r;
      int d = nt * 16 + fr;
      O[(size_t)(q * 16 + b) * 512 + h * 64 + d] = f2bf(oc[nt][r]);
    }
  }
}

// ---------------- batched bf16 MFMA GEMM: direct global->VGPR fragments -----
// X: bf16 [M,K] K-major, W: bf16 [N,K] K-major. No LDS, no barriers: fragment
// slabs (8KB) are L1-resident, weights L2-hot across M-blocks.
struct GemmJob {
  const unsigned short* X;
  const unsigned short* W;
  const float* bias;
  const float* resid;
  float* Y;
  unsigned short* Ybf;
  float scale;
  int relu;
};
struct GemmBatch {
  GemmJob j[5];
};

__global__ __launch_bounds__(256) void gemm_bf16(GemmBatch gb, int M, int N,
                                                 int K) {
  const GemmJob jb = gb.j[blockIdx.z];
  const int t = threadIdx.x;
  const int lane = t & 63;
  const int wave = t >> 6;
  const int wr = wave >> 1;
  const int wc = wave & 1;
  const int bm = blockIdx.y * 64;
  const int bn = blockIdx.x * 64;
  const int fr = lane & 15, fg = lane >> 4;

  f32x4 acc[2][2] = {};
  // A fragment rows: bm + wr*32 + {0,16} + fr ; k = k0 + ks*32 + fg*8
  const unsigned short* Xp = jb.X + (size_t)(bm + wr * 32 + fr) * K + fg * 8;
  const unsigned short* Wp = jb.W + (size_t)(bn + wc * 32 + fr) * K + fg * 8;
  const size_t row16 = (size_t)16 * K;

  for (int k0 = 0; k0 < K; k0 += 64) {
#pragma unroll
    for (int ks = 0; ks < 2; ++ks) {
      int kk = k0 + ks * 32;
      bf16x8 a0 = *(const bf16x8*)(Xp + kk);
      bf16x8 a1 = *(const bf16x8*)(Xp + row16 + kk);
      bf16x8 b0 = *(const bf16x8*)(Wp + kk);
      bf16x8 b1 = *(const bf16x8*)(Wp + row16 + kk);
      acc[0][0] = __builtin_amdgcn_mfma_f32_16x16x32_bf16(a0, b0, acc[0][0], 0, 0, 0);
      acc[0][1] = __builtin_amdgcn_mfma_f32_16x16x32_bf16(a0, b1, acc[0][1], 0, 0, 0);
      acc[1][0] = __builtin_amdgcn_mfma_f32_16x16x32_bf16(a1, b0, acc[1][0], 0, 0, 0);
      acc[1][1] = __builtin_amdgcn_mfma_f32_16x16x32_bf16(a1, b1, acc[1][1], 0, 0, 0);
    }
  }
  // epilogue: C/D layout col = lane&15, row = (lane>>4)*4 + r
#pragma unroll
  for (int mt = 0; mt < 2; ++mt) {
#pragma unroll
    for (int nt = 0; nt < 2; ++nt) {
      int col = bn + wc * 32 + nt * 16 + fr;
      int rowb = bm + wr * 32 + mt * 16 + fg * 4;
      float bia = jb.bias ? jb.bias[col] : 0.f;
#pragma unroll
      for (int r = 0; r < 4; ++r) {
        float v = (acc[mt][nt][r] + bia) * jb.scale;
        if (jb.relu) v = fmaxf(v, 0.f);
        if (jb.resid) v += jb.resid[(size_t)(rowb + r) * N + col];
        size_t idx = (size_t)(rowb + r) * N + col;
        if (jb.Y) jb.Y[idx] = v;
        if (jb.Ybf) jb.Ybf[idx] = f2bf(v);
      }
    }
  }
}

extern "C" void kernel_launch(void* const* d_in, const int* in_sizes, int n_in,
                              void* d_out, int out_size, void* d_ws,
                              size_t ws_size, hipStream_t stream) {
  const float* enc = (const float*)d_in[0];
  const float* dec = (const float*)d_in[1];
  const float* ec_Wi = (const float*)d_in[2];
  const float* ec_bi = (const float*)d_in[3];
  const float* ec_Wo = (const float*)d_in[4];
  const float* ec_bo = (const float*)d_in[5];
  const float* dc_Wi = (const float*)d_in[6];
  const float* dc_bi = (const float*)d_in[7];
  const float* dc_Wo = (const float*)d_in[8];
  const float* dc_bo = (const float*)d_in[9];
  const float* es_Wi = (const float*)d_in[10];
  const float* es_bi = (const float*)d_in[11];
  const float* es_Wo = (const float*)d_in[12];
  const float* es_bo = (const float*)d_in[13];
  const float* ds_Wi = (const float*)d_in[14];
  const float* ds_bi = (const float*)d_in[15];
  const float* ds_Wo = (const float*)d_in[16];
  const float* ds_bo = (const float*)d_in[17];
  const float* eff_W1 = (const float*)d_in[18];
  const float* eff_b1 = (const float*)d_in[19];
  const float* eff_W2 = (const float*)d_in[20];
  const float* eff_b2 = (const float*)d_in[21];
  const float* dff_W1 = (const float*)d_in[22];
  const float* dff_b1 = (const float*)d_in[23];
  const float* dff_W2 = (const float*)d_in[24];
  const float* dff_b2 = (const float*)d_in[25];
  const float* n_ec_g = (const float*)d_in[26];
  const float* n_ec_b = (const float*)d_in[27];
  const float* n_es_g = (const float*)d_in[28];
  const float* n_es_b = (const float*)d_in[29];
  const float* n_ef_g = (const float*)d_in[30];
  const float* n_ef_b = (const float*)d_in[31];
  const float* n_dci_g = (const float*)d_in[34];
  const float* n_dci_b = (const float*)d_in[35];
  const float* n_ds_g = (const float*)d_in[36];
  const float* n_ds_b = (const float*)d_in[37];
  const float* n_df_g = (const float*)d_in[38];
  const float* n_df_b = (const float*)d_in[39];
  const float* pW = (const float*)d_in[40];
  const float* pWb = (const float*)d_in[41];
  const float* pv = (const float*)d_in[42];
  const float* pb = (const float*)d_in[43];

  float* ws = (float*)d_ws;
  const size_t U = 524288;  // 1024*512 elements
  float* Ed = ws + 3 * U;
  float* tb = ws + 4 * U;
  float* Et = ws + 7 * U;
  float* enc1 = ws + 8 * U;
  float* dec1 = ws + 9 * U;
  float* enc2 = ws + 10 * U;
  float* dec2 = ws + 11 * U;
  float* sm = ws + 12 * U;
  float* md = sm;
  float* q2d = sm + 1024;
  float* mt = sm + 2048;
  float* q2t = sm + 3072;
  float* u_k = sm + 4096;
  float* u_v = sm + 4608;
  float* c_k = sm + 5120;
  float* c_v = sm + 5632;
  float* mArr = sm + 6144;           // b-major [b][j][i], 65536
  float* rArr = sm + 6144 + 65536;
  unsigned short* ub0 = (unsigned short*)ws;
  unsigned short* Qe_b = ub0 + 0 * U;
  unsigned short* Kd_b = ub0 + 1 * U;
  unsigned short* Vd_b = ub0 + 2 * U;
  unsigned short* Kt_b = ub0 + 3 * U;
  unsigned short* Vt_b = ub0 + 4 * U;
  unsigned short* ub = (unsigned short*)(ws + 12 * U + 137216);
  const int W262 = 262144, W786 = 786432, W1M = 1048576;
  unsigned short* w_dcWv = ub;
  unsigned short* w_ecWq = w_dcWv + W262;
  unsigned short* w_ecWkg = w_ecWq + W262;
  unsigned short* w_ecWvg = w_ecWkg + W262;
  unsigned short* w_pW = w_ecWvg + W262;
  unsigned short* w_dcWo = w_pW + W262;
  unsigned short* w_ecWo = w_dcWo + W262;
  unsigned short* w_esWi = w_ecWo + W262;
  unsigned short* w_dsWi = w_esWi + W786;
  unsigned short* w_esWo = w_dsWi + W786;
  unsigned short* w_dsWo = w_esWo + W262;
  unsigned short* w_effW1 = w_dsWo + W262;
  unsigned short* w_dffW1 = w_effW1 + W1M;
  unsigned short* w_effW2 = w_dffW1 + W1M;
  unsigned short* w_dffW2 = w_effW2 + W1M;
  unsigned short* actb = w_dffW2 + W1M;
  unsigned short* f_n_b = actb;
  unsigned short* V1_b = actb + U;
  unsigned short* dec_b = actb + 2 * U;
  unsigned short* tb_b = actb + 3 * U;
  unsigned short* Oec_b = actb + 4 * U;
  unsigned short* nbE = f_n_b;
  unsigned short* nbD = V1_b;
  unsigned short* OaE = dec_b;
  unsigned short* OaD = tb_b;
  unsigned short* QKVe_b = (unsigned short*)(ws + 0 * U);
  unsigned short* QKVd_b = (unsigned short*)(ws + 2 * U);
  unsigned short* He_b = (unsigned short*)(ws + 0 * U);
  unsigned short* Hd_b = (unsigned short*)(ws + 2 * U);

  const float* dc_Wv = dc_Wi + 1024 * 512;
  const float* dc_bv = dc_bi + 1024;
  const float* ec_Wq = ec_Wi;
  const float* ec_bq = ec_bi;
  const float* ec_Wk = ec_Wi + 512 * 512;
  const float* ec_bk = ec_bi + 512;
  const float* ec_Wv = ec_Wi + 1024 * 512;
  const float* ec_bv = ec_bi + 1024;

  // 0. weight casts
  {
    CastBatch cb{};
    cb.j[0] = {dc_Wv, w_dcWv, W262, nullptr};
    cb.j[1] = {ec_Wq, w_ecWq, W262, nullptr};
    cb.j[2] = {ec_Wk, w_ecWkg, W262, n_dci_g};
    cb.j[3] = {ec_Wv, w_ecWvg, W262, n_dci_g};
    cb.j[4] = {pW, w_pW, W262, nullptr};
    cb.j[5] = {dc_Wo, w_dcWo, W262, nullptr};
    cb.j[6] = {ec_Wo, w_ecWo, W262, nullptr};
    cb.j[7] = {es_Wi, w_esWi, W786, nullptr};
    cb.j[8] = {ds_Wi, w_dsWi, W786, nullptr};
    cb.j[9] = {es_Wo, w_esWo, W262, nullptr};
    cb.j[10] = {ds_Wo, w_dsWo, W262, nullptr};
    cb.j[11] = {eff_W1, w_effW1, W1M, nullptr};
    cb.j[12] = {dff_W1, w_dffW1, W1M, nullptr};
    cb.j[13] = {eff_W2, w_effW2, W1M, nullptr};
    cb.j[14] = {dff_W2, w_dffW2, W1M, nullptr};
    cast_w<<<dim3(32, 15), 256, 0, stream>>>(cb);
  }
  // 1+2. LN(enc)->bf16 fused with dec stats+cast
  ln_stats_kernel<<<2048, 256, 0, stream>>>(enc, n_ec_g, n_ec_b, f_n_b, dec,
                                            md, q2d, dec_b);
  // 3. u/c vectors
  uvec_kernel<<<128, 256, 0, stream>>>(ec_Wk, ec_Wv, ec_bk, ec_bv, n_dci_g,
                                       n_dci_b, u_k, u_v, c_k, c_v);
  // 4. batch A
  {
    GemmBatch gb{};
    gb.j[0] = {f_n_b, w_dcWv, dc_bv, nullptr, nullptr, V1_b, 1.f, 0};
    gb.j[1] = {f_n_b, w_ecWq, ec_bq, nullptr, nullptr, Qe_b, 0.125f, 0};
    gb.j[2] = {dec_b, w_ecWkg, nullptr, nullptr, nullptr, Kd_b, 1.f, 0};
    gb.j[3] = {dec_b, w_ecWvg, nullptr, nullptr, nullptr, Vd_b, 1.f, 0};
    gb.j[4] = {dec_b, w_pW, pWb, nullptr, Ed, nullptr, 1.f, 0};
    gemm_bf16<<<dim3(8, 16, 5), 256, 0, stream>>>(gb, 1024, 512, 512);
  }
  // 5. t = V1 @ dc_Wo^T + dc_bo
  {
    GemmBatch gb{};
    gb.j[0] = {V1_b, w_dcWo, dc_bo, nullptr, tb, tb_b, 1.f, 0};
    gemm_bf16<<<dim3(8, 16, 1), 256, 0, stream>>>(gb, 1024, 512, 512);
  }
  // 6. t row stats
  stats_kernel<<<1024, 256, 0, stream>>>(tb, mt, q2t, nullptr);
  // 7. batch B
  {
    GemmBatch gb{};
    gb.j[0] = {tb_b, w_ecWkg, nullptr, nullptr, nullptr, Kt_b, 1.f, 0};
    gb.j[1] = {tb_b, w_ecWvg, nullptr, nullptr, nullptr, Vt_b, 1.f, 0};
    gb.j[2] = {tb_b, w_pW, pb, nullptr, Et, nullptr, 1.f, 0};
    gemm_bf16<<<dim3(8, 16, 3), 256, 0, stream>>>(gb, 1024, 512, 512);
  }
  // 8. per-(j,i,b) LN stats
  mr_kernel<<<16384, 256, 0, stream>>>(dec, tb, md, q2d, mt, q2t, mArr, rArr);
  // 9. ec cross-attention (MFMA)
  ec_attn<<<128, 256, 0, stream>>>(Qe_b, Kd_b, Kt_b, Vd_b, Vt_b, u_k, u_v, c_k,
                                   c_v, mArr, rArr, Oec_b);
  // 10. pooling -> dec1
  pool_kernel<<<dim3(64, 16), 256, 0, stream>>>(Ed, Et, pv, dec, tb_b, dec1);
  // 11. enc1 = enc + O_ec @ ec_Wo^T + ec_bo
  {
    GemmBatch gb{};
    gb.j[0] = {Oec_b, w_ecWo, ec_bo, enc, enc1, nullptr, 1.f, 0};
    gemm_bf16<<<dim3(8, 16, 1), 256, 0, stream>>>(gb, 1024, 512, 512);
  }
  // 12. pre-norm for self-attention
  ln2_kernel<<<2048, 256, 0, stream>>>(enc1, n_es_g, n_es_b, nbE, dec1, n_ds_g,
                                       n_ds_b, nbD);
  // 13. QKV projections
  {
    GemmBatch gb{};
    gb.j[0] = {nbE, w_esWi, es_bi, nullptr, nullptr, QKVe_b, 1.f, 0};
    gb.j[1] = {nbD, w_dsWi, ds_bi, nullptr, nullptr, QKVd_b, 1.f, 0};
    gemm_bf16<<<dim3(24, 16, 2), 256, 0, stream>>>(gb, 1024, 1536, 512);
  }
  // 14. self-attention cores (MFMA)
  self_attn<<<dim3(128, 2), 256, 0, stream>>>(QKVe_b, OaE, QKVd_b, OaD);
  // 15. output proj + residual
  {
    GemmBatch gb{};
    gb.j[0] = {OaE, w_esWo, es_bo, enc1, enc2, nullptr, 1.f, 0};
    gb.j[1] = {OaD, w_dsWo, ds_bo, dec1, dec2, nullptr, 1.f, 0};
    gemm_bf16<<<dim3(8, 16, 2), 256, 0, stream>>>(gb, 1024, 512, 512);
  }
  // 16. pre-norm for FFN
  ln2_kernel<<<2048, 256, 0, stream>>>(enc2, n_ef_g, n_ef_b, nbE, dec2, n_df_g,
                                       n_df_b, nbD);
  // 17. FFN layer 1 (relu)
  {
    GemmBatch gb{};
    gb.j[0] = {nbE, w_effW1, eff_b1, nullptr, nullptr, He_b, 1.f, 1};
    gb.j[1] = {nbD, w_dffW1, dff_b1, nullptr, nullptr, Hd_b, 1.f, 1};
    gemm_bf16<<<dim3(32, 16, 2), 256, 0, stream>>>(gb, 1024, 2048, 512);
  }
  // 18. FFN layer 2 + residual -> outputs
  float* out = (float*)d_out;
  {
    GemmBatch gb{};
    gb.j[0] = {He_b, w_effW2, eff_b2, enc2, out, nullptr, 1.f, 0};
    gb.j[1] = {Hd_b, w_dffW2, dff_b2, dec2, out + U, nullptr, 1.f, 0};
    gemm_bf16<<<dim3(8, 16, 2), 256, 0, stream>>>(gb, 1024, 512, 2048);
  }
}

// Round 9
// 312.210 us; speedup vs baseline: 1.2936x; 1.2936x over previous
//
#include <hip/hip_runtime.h>

// Problem constants: D=512, H=8 (hd=64), DFF=2048, NE=64, ND=64, B=16
// Identities exploited:
//  - dc cross-attention has softmax over 1 key -> t[j,b] = Wo(Wv f_n[j,b]+bv)+bo
//  - G_fj[j,i,b] = dec[i,b] + t[j,b]  (rank-decomposed; never materialized)
//  - LN(G_fj) linearity: K/V projections & pooling energy decompose into
//    per-i and per-j 1024-row GEMMs + scalar stats m[j,i,b], r[j,i,b].
// R2: bf16 MFMA GEMMs. R4: all-bf16 (L2-resident). R5-R7: pool/self/ec MFMA.
// R8 FAILED: no-LDS GEMM regressed 321->404 (fragment loads uncoalesced:
// fr-lanes stride K*2B -> 64 cache lines per wave load). R9: revert to R7
// LDS GEMM; keep ln_stats fusion; mr_kernel reads bf16 (2 loads/wave-row).

typedef __bf16 bf16_t;
typedef bf16_t bf16x8 __attribute__((ext_vector_type(8)));
typedef float f32x4 __attribute__((ext_vector_type(4)));
typedef unsigned short u16x4 __attribute__((ext_vector_type(4)));
typedef unsigned short u16x8 __attribute__((ext_vector_type(8)));

__device__ inline unsigned short f2bf(float f) {
  unsigned int u = __float_as_uint(f);
  u += 0x7fffu + ((u >> 16) & 1u);  // RNE
  return (unsigned short)(u >> 16);
}
__device__ inline float bf2f(unsigned short u) {
  return __uint_as_float(((unsigned int)u) << 16);
}

__device__ inline float wsum(float v) {
#pragma unroll
  for (int o = 1; o < 64; o <<= 1) v += __shfl_xor(v, o);
  return v;
}
__device__ inline float wmax(float v) {
#pragma unroll
  for (int o = 1; o < 64; o <<= 1) v = fmaxf(v, __shfl_xor(v, o));
  return v;
}

// ---------------- weight cast fp32 -> bf16 (optional per-K colscale) --------
struct CastJob {
  const float* src;
  unsigned short* dst;
  int n;
  const float* cs;  // per-(i & 511) scale or null
};
struct CastBatch {
  CastJob j[15];
};

__global__ __launch_bounds__(256) void cast_w(CastBatch cb) {
  const CastJob jb = cb.j[blockIdx.y];
  const int stride = 32 * 256 * 4;
  for (int i = (blockIdx.x * 256 + threadIdx.x) * 4; i < jb.n; i += stride) {
    float4 v = *(const float4*)(jb.src + i);
    if (jb.cs) {
      int k = i & 511;
      v.x *= jb.cs[k];
      v.y *= jb.cs[k + 1];
      v.z *= jb.cs[k + 2];
      v.w *= jb.cs[k + 3];
    }
    u16x4 o = {f2bf(v.x), f2bf(v.y), f2bf(v.z), f2bf(v.w)};
    *(u16x4*)(jb.dst + i) = o;
  }
}

// ---------------- LayerNorm over last dim (512) -> bf16 out -----------------
__device__ inline void ln_body(const float* __restrict__ x,
                               const float* __restrict__ g,
                               const float* __restrict__ be,
                               unsigned short* __restrict__ y, int t) {
  float v0 = x[t], v1 = x[t + 256];
  float s = wsum(v0 + v1);
  float s2 = wsum(v0 * v0 + v1 * v1);
  __shared__ float sh[8];
  int w = t >> 6, lane = t & 63;
  if (lane == 0) { sh[w] = s; sh[4 + w] = s2; }
  __syncthreads();
  s = sh[0] + sh[1] + sh[2] + sh[3];
  s2 = sh[4] + sh[5] + sh[6] + sh[7];
  float mean = s * (1.f / 512.f);
  float var = s2 * (1.f / 512.f) - mean * mean;
  float r = rsqrtf(var + 1e-5f);
  y[t] = f2bf((v0 - mean) * r * g[t] + be[t]);
  y[t + 256] = f2bf((v1 - mean) * r * g[t + 256] + be[t + 256]);
}

__device__ inline void stats_body(const float* __restrict__ x,
                                  float* __restrict__ m, float* __restrict__ q2,
                                  unsigned short* __restrict__ xb, int t,
                                  int row) {
  float v0 = x[t], v1 = x[t + 256];
  if (xb) {
    xb[t] = f2bf(v0);
    xb[t + 256] = f2bf(v1);
  }
  float s = wsum(v0 + v1);
  float s2 = wsum(v0 * v0 + v1 * v1);
  __shared__ float sh2[8];
  int w = t >> 6, lane = t & 63;
  if (lane == 0) { sh2[w] = s; sh2[4 + w] = s2; }
  __syncthreads();
  if (t == 0) {
    s = sh2[0] + sh2[1] + sh2[2] + sh2[3];
    s2 = sh2[4] + sh2[5] + sh2[6] + sh2[7];
    m[row] = s * (1.f / 512.f);
    q2[row] = s2 * (1.f / 512.f);
  }
}

// fused: rows<1024 -> LN(enc)->f_n_b; rows>=1024 -> stats(dec)+cast->dec_b
__global__ __launch_bounds__(256) void ln_stats_kernel(
    const float* __restrict__ enc, const float* __restrict__ g,
    const float* __restrict__ be, unsigned short* __restrict__ f_n,
    const float* __restrict__ dec, float* __restrict__ md,
    float* __restrict__ q2d, unsigned short* __restrict__ dec_b) {
  int row = blockIdx.x;
  if (row < 1024) {
    ln_body(enc + (size_t)row * 512, g, be, f_n + (size_t)row * 512,
            threadIdx.x);
  } else {
    row -= 1024;
    stats_body(dec + (size_t)row * 512, md, q2d, dec_b + (size_t)row * 512,
               threadIdx.x, row);
  }
}

__global__ __launch_bounds__(256) void stats_kernel(
    const float* __restrict__ X, float* __restrict__ m, float* __restrict__ q2,
    unsigned short* __restrict__ Xb) {
  int row = blockIdx.x;
  stats_body(X + (size_t)row * 512, m, q2,
             Xb ? Xb + (size_t)row * 512 : nullptr, threadIdx.x, row);
}

__global__ __launch_bounds__(256) void ln2_kernel(
    const float* __restrict__ X0, const float* __restrict__ g0,
    const float* __restrict__ b0, unsigned short* __restrict__ Y0,
    const float* __restrict__ X1, const float* __restrict__ g1,
    const float* __restrict__ b1, unsigned short* __restrict__ Y1) {
  int row = blockIdx.x;
  if (row < 1024) {
    ln_body(X0 + (size_t)row * 512, g0, b0, Y0 + (size_t)row * 512, threadIdx.x);
  } else {
    row -= 1024;
    ln_body(X1 + (size_t)row * 512, g1, b1, Y1 + (size_t)row * 512, threadIdx.x);
  }
}

// ---------------- u/c vectors: one wave per output row ----------------------
__global__ __launch_bounds__(256) void uvec_kernel(
    const float* __restrict__ Wk, const float* __restrict__ Wv,
    const float* __restrict__ bk, const float* __restrict__ bv,
    const float* __restrict__ g, const float* __restrict__ beta,
    float* __restrict__ u_k, float* __restrict__ u_v,
    float* __restrict__ c_k, float* __restrict__ c_v) {
  int n = blockIdx.x * 4 + (threadIdx.x >> 6);
  int lane = threadIdx.x & 63;
  const float* wk = Wk + (size_t)n * 512;
  const float* wv = Wv + (size_t)n * 512;
  float uk = 0.f, uv = 0.f, ck = 0.f, cv = 0.f;
#pragma unroll
  for (int k0 = 0; k0 < 512; k0 += 64) {
    int k = k0 + lane;
    float a = wk[k], b2 = wv[k], gg = g[k], bb = beta[k];
    uk += a * gg;
    ck += a * bb;
    uv += b2 * gg;
    cv += b2 * bb;
  }
  uk = wsum(uk);
  uv = wsum(uv);
  ck = wsum(ck);
  cv = wsum(cv);
  if (lane == 0) {
    u_k[n] = uk;
    u_v[n] = uv;
    c_k[n] = ck + bk[n];
    c_v[n] = cv + bv[n];
  }
}

// ---------------- per-(j,i,b) LN stats, bf16 inputs, out b-major [b][j][i] --
__global__ __launch_bounds__(256) void mr_kernel(
    const unsigned short* __restrict__ decb, const unsigned short* __restrict__ tbb,
    const float* __restrict__ md, const float* __restrict__ q2d,
    const float* __restrict__ mt, const float* __restrict__ q2t,
    float* __restrict__ mArr, float* __restrict__ rArr) {
  int wid = blockIdx.x * 4 + (threadIdx.x >> 6);
  int lane = threadIdx.x & 63;
  int b = wid & 15;
  int i = (wid >> 4) & 63;
  int j = wid >> 10;
  const unsigned short* dr = decb + (size_t)(i * 16 + b) * 512 + lane * 8;
  const unsigned short* tr = tbb + (size_t)(j * 16 + b) * 512 + lane * 8;
  u16x8 a = *(const u16x8*)dr;
  u16x8 c = *(const u16x8*)tr;
  float s = 0.f;
#pragma unroll
  for (int k = 0; k < 8; ++k) s += bf2f(a[k]) * bf2f(c[k]);
  s = wsum(s);
  if (lane == 0) {
    float mean = md[i * 16 + b] + mt[j * 16 + b];
    float msq = q2d[i * 16 + b] + q2t[j * 16 + b] + 2.f * s * (1.f / 512.f);
    float var = msq - mean * mean;
    int idx = b * 4096 + j * 64 + i;
    mArr[idx] = mean;
    rArr[idx] = rsqrtf(var + 1e-5f);
  }
}

// ---------------- ec cross-attention: MFMA flash block per (b,h) ------------
__global__ __launch_bounds__(256) void ec_attn(
    const unsigned short* __restrict__ Qe, const unsigned short* __restrict__ Kd,
    const unsigned short* __restrict__ Kt, const unsigned short* __restrict__ Vd,
    const unsigned short* __restrict__ Vt, const float* __restrict__ u_k,
    const float* __restrict__ u_v, const float* __restrict__ c_k,
    const float* __restrict__ c_v, const float* __restrict__ mArr,
    const float* __restrict__ rArr, unsigned short* __restrict__ O) {
  int h = blockIdx.x & 7;
  int b = blockIdx.x >> 3;
  __shared__ unsigned short Qs[64][72];
  __shared__ unsigned short Ks[64][72];
  __shared__ unsigned short VdT[64][72];
  __shared__ unsigned short Ps[64][72];
  __shared__ float ms[64][66];
  __shared__ float rs[64][66];
  __shared__ float stp[64][4], sup[64][4], scp[64][4];
  __shared__ float stv[64], suv[64], scv[64], swv[64], swmv[64];
  int t = threadIdx.x;
  {
    int row = t >> 2;
    int qt = t & 3;
    int cb = qt * 16;
    size_t base = (size_t)(row * 16 + b) * 512 + h * 64 + cb;
    u16x8 q0 = *(const u16x8*)(Qe + base);
    u16x8 q1 = *(const u16x8*)(Qe + base + 8);
    u16x8 k0 = *(const u16x8*)(Kd + base);
    u16x8 k1 = *(const u16x8*)(Kd + base + 8);
    u16x8 kt0 = *(const u16x8*)(Kt + base);
    u16x8 kt1 = *(const u16x8*)(Kt + base + 8);
    u16x8 v0 = *(const u16x8*)(Vd + base);
    u16x8 v1 = *(const u16x8*)(Vd + base + 8);
    *(u16x8*)&Qs[row][cb] = q0;
    *(u16x8*)&Qs[row][cb + 8] = q1;
    *(u16x8*)&Ks[row][cb] = k0;
    *(u16x8*)&Ks[row][cb + 8] = k1;
#pragma unroll
    for (int jj = 0; jj < 8; ++jj) VdT[cb + jj][row] = v0[jj];
#pragma unroll
    for (int jj = 0; jj < 8; ++jj) VdT[cb + 8 + jj][row] = v1[jj];
    float st_ = 0.f, su_ = 0.f, sc_ = 0.f;
#pragma unroll
    for (int jj = 0; jj < 8; ++jj) {
      float qa = bf2f(q0[jj]), qb = bf2f(q1[jj]);
      st_ += qa * bf2f(kt0[jj]) + qb * bf2f(kt1[jj]);
      su_ += qa * u_k[h * 64 + cb + jj] + qb * u_k[h * 64 + cb + 8 + jj];
      sc_ += qa * c_k[h * 64 + cb + jj] + qb * c_k[h * 64 + cb + 8 + jj];
    }
    stp[row][qt] = st_;
    sup[row][qt] = su_;
    scp[row][qt] = sc_;
  }
#pragma unroll
  for (int k = 0; k < 16; ++k) {
    int idx = t + k * 256;
    ms[idx >> 6][idx & 63] = mArr[(size_t)b * 4096 + idx];
    rs[idx >> 6][idx & 63] = rArr[(size_t)b * 4096 + idx];
  }
  __syncthreads();
  if (t < 64) {
    stv[t] = stp[t][0] + stp[t][1] + stp[t][2] + stp[t][3];
    suv[t] = sup[t][0] + sup[t][1] + sup[t][2] + sup[t][3];
    scv[t] = scp[t][0] + scp[t][1] + scp[t][2] + scp[t][3];
  }
  __syncthreads();
  int wave = t >> 6, lane = t & 63;
  int fr = lane & 15, fg = lane >> 4;
  f32x4 sacc[4] = {};
  bf16x8 aq0 = *(const bf16x8*)&Qs[wave * 16 + fr][fg * 8];
  bf16x8 aq1 = *(const bf16x8*)&Qs[wave * 16 + fr][32 + fg * 8];
#pragma unroll
  for (int nt = 0; nt < 4; ++nt) {
    bf16x8 b0 = *(const bf16x8*)&Ks[nt * 16 + fr][fg * 8];
    bf16x8 b1 = *(const bf16x8*)&Ks[nt * 16 + fr][32 + fg * 8];
    sacc[nt] = __builtin_amdgcn_mfma_f32_16x16x32_bf16(aq0, b0, sacc[nt], 0, 0, 0);
    sacc[nt] = __builtin_amdgcn_mfma_f32_16x16x32_bf16(aq1, b1, sacc[nt], 0, 0, 0);
  }
#pragma unroll
  for (int r = 0; r < 4; ++r) {
    int j = wave * 16 + fg * 4 + r;
    float stj = stv[j], suj = suv[j], scj = scv[j];
    float a0, a1, a2, a3;
    {
      int i0 = fr, i1 = 16 + fr, i2 = 32 + fr, i3 = 48 + fr;
      a0 = rs[j][i0] * (sacc[0][r] + stj - ms[j][i0] * suj) + scj;
      a1 = rs[j][i1] * (sacc[1][r] + stj - ms[j][i1] * suj) + scj;
      a2 = rs[j][i2] * (sacc[2][r] + stj - ms[j][i2] * suj) + scj;
      a3 = rs[j][i3] * (sacc[3][r] + stj - ms[j][i3] * suj) + scj;
    }
    float mx = fmaxf(fmaxf(a0, a1), fmaxf(a2, a3));
#pragma unroll
    for (int o = 1; o < 16; o <<= 1) mx = fmaxf(mx, __shfl_xor(mx, o));
    a0 = __expf(a0 - mx);
    a1 = __expf(a1 - mx);
    a2 = __expf(a2 - mx);
    a3 = __expf(a3 - mx);
    float se = a0 + a1 + a2 + a3;
#pragma unroll
    for (int o = 1; o < 16; o <<= 1) se += __shfl_xor(se, o);
    float inv = 1.f / se;
    float w0 = a0 * inv * rs[j][fr];
    float w1 = a1 * inv * rs[j][16 + fr];
    float w2 = a2 * inv * rs[j][32 + fr];
    float w3 = a3 * inv * rs[j][48 + fr];
    float sw = w0 + w1 + w2 + w3;
    float swm = w0 * ms[j][fr] + w1 * ms[j][16 + fr] + w2 * ms[j][32 + fr] +
                w3 * ms[j][48 + fr];
#pragma unroll
    for (int o = 1; o < 16; o <<= 1) {
      sw += __shfl_xor(sw, o);
      swm += __shfl_xor(swm, o);
    }
    Ps[j][fr] = f2bf(w0);
    Ps[j][16 + fr] = f2bf(w1);
    Ps[j][32 + fr] = f2bf(w2);
    Ps[j][48 + fr] = f2bf(w3);
    if (fr == 0) {
      swv[j] = sw;
      swmv[j] = swm;
    }
  }
  f32x4 oc[4] = {};
  bf16x8 ap0 = *(const bf16x8*)&Ps[wave * 16 + fr][fg * 8];
  bf16x8 ap1 = *(const bf16x8*)&Ps[wave * 16 + fr][32 + fg * 8];
#pragma unroll
  for (int nt = 0; nt < 4; ++nt) {
    bf16x8 b0 = *(const bf16x8*)&VdT[nt * 16 + fr][fg * 8];
    bf16x8 b1 = *(const bf16x8*)&VdT[nt * 16 + fr][32 + fg * 8];
    oc[nt] = __builtin_amdgcn_mfma_f32_16x16x32_bf16(ap0, b0, oc[nt], 0, 0, 0);
    oc[nt] = __builtin_amdgcn_mfma_f32_16x16x32_bf16(ap1, b1, oc[nt], 0, 0, 0);
  }
#pragma unroll
  for (int nt = 0; nt < 4; ++nt) {
    int d = nt * 16 + fr;
    float uvd = u_v[h * 64 + d];
    float cvd = c_v[h * 64 + d];
#pragma unroll
    for (int r = 0; r < 4; ++r) {
      int j = wave * 16 + fg * 4 + r;
      size_t gidx = (size_t)(j * 16 + b) * 512 + h * 64 + d;
      float o = oc[nt][r] + swv[j] * bf2f(Vt[gidx]) - swmv[j] * uvd + cvd;
      O[gidx] = f2bf(o);
    }
  }
}

// ---------------- attention pooling: coalesced, wave-per-16j ----------------
__global__ __launch_bounds__(256) void pool_kernel(
    const float* __restrict__ Ed, const float* __restrict__ Et,
    const float* __restrict__ pv, const float* __restrict__ dec,
    const unsigned short* __restrict__ tbf, float* __restrict__ dec1) {
  int i = blockIdx.x;
  int b = blockIdx.y;
  int t = threadIdx.x;
  int wave = t >> 6, lane = t & 63;
  float edv[8], pvv[8];
  const float* ed = Ed + (size_t)(i * 16 + b) * 512;
#pragma unroll
  for (int c = 0; c < 8; ++c) {
    edv[c] = ed[c * 64 + lane];
    pvv[c] = pv[c * 64 + lane];
  }
  __shared__ float esh[64];
  __shared__ float wsh[64];
#pragma unroll 1
  for (int jl = 0; jl < 16; ++jl) {
    int j = wave * 16 + jl;
    const float* et = Et + (size_t)(j * 16 + b) * 512;
    float s = 0.f;
#pragma unroll
    for (int c = 0; c < 8; ++c) {
      float x = edv[c] + et[c * 64 + lane];
      float e2 = __expf(2.f * x);
      float th = 1.f - 2.f * __builtin_amdgcn_rcpf(e2 + 1.f);  // tanh
      s += th * pvv[c];
    }
    s = wsum(s);
    if (lane == 0) esh[j] = s;
  }
  __syncthreads();
  if (t < 64) {
    float e = esh[t];
    float mx = wmax(e);
    float ex = __expf(e - mx);
    float se = wsum(ex);
    wsh[t] = ex / se;
  }
  __syncthreads();
  size_t rowib = (size_t)(i * 16 + b) * 512;
  int d2 = t * 2;
  float2 dv = *(const float2*)(dec + rowib + d2);
  float acc0 = dv.x, acc1 = dv.y;
#pragma unroll 8
  for (int j2 = 0; j2 < 64; ++j2) {
    const unsigned short* tp = tbf + (size_t)(j2 * 16 + b) * 512 + d2;
    float w = wsh[j2];
    acc0 += w * bf2f(tp[0]);
    acc1 += w * bf2f(tp[1]);
  }
  float2 ov = {acc0, acc1};
  *(float2*)(dec1 + rowib + d2) = ov;
}

// ---------------- MFMA self-attention: one block per (b,h) ------------------
__global__ __launch_bounds__(256) void self_attn(
    const unsigned short* __restrict__ QKVe, unsigned short* __restrict__ Oe,
    const unsigned short* __restrict__ QKVd, unsigned short* __restrict__ Od) {
  const unsigned short* QKV = blockIdx.y ? QKVd : QKVe;
  unsigned short* O = blockIdx.y ? Od : Oe;
  int h = blockIdx.x & 7;
  int b = blockIdx.x >> 3;
  __shared__ unsigned short Qs[64][72];
  __shared__ unsigned short Ksh[64][72];
  __shared__ unsigned short VT[64][72];
  __shared__ unsigned short Ps[64][72];
  int t = threadIdx.x;
  {
    int row = t >> 2;
    int cb = (t & 3) * 16;
    const unsigned short* src =
        QKV + (size_t)(row * 16 + b) * 1536 + h * 64 + cb;
    u16x8 q0 = *(const u16x8*)(src);
    u16x8 q1 = *(const u16x8*)(src + 8);
    u16x8 k0 = *(const u16x8*)(src + 512);
    u16x8 k1 = *(const u16x8*)(src + 520);
    u16x8 v0 = *(const u16x8*)(src + 1024);
    u16x8 v1 = *(const u16x8*)(src + 1032);
    *(u16x8*)&Qs[row][cb] = q0;
    *(u16x8*)&Qs[row][cb + 8] = q1;
    *(u16x8*)&Ksh[row][cb] = k0;
    *(u16x8*)&Ksh[row][cb + 8] = k1;
#pragma unroll
    for (int jj = 0; jj < 8; ++jj) VT[cb + jj][row] = v0[jj];
#pragma unroll
    for (int jj = 0; jj < 8; ++jj) VT[cb + 8 + jj][row] = v1[jj];
  }
  __syncthreads();
  int wave = t >> 6, lane = t & 63;
  int fr = lane & 15, fg = lane >> 4;
  f32x4 sc[4] = {};
  bf16x8 aq0 = *(const bf16x8*)&Qs[wave * 16 + fr][fg * 8];
  bf16x8 aq1 = *(const bf16x8*)&Qs[wave * 16 + fr][32 + fg * 8];
#pragma unroll
  for (int nt = 0; nt < 4; ++nt) {
    bf16x8 b0 = *(const bf16x8*)&Ksh[nt * 16 + fr][fg * 8];
    bf16x8 b1 = *(const bf16x8*)&Ksh[nt * 16 + fr][32 + fg * 8];
    sc[nt] = __builtin_amdgcn_mfma_f32_16x16x32_bf16(aq0, b0, sc[nt], 0, 0, 0);
    sc[nt] = __builtin_amdgcn_mfma_f32_16x16x32_bf16(aq1, b1, sc[nt], 0, 0, 0);
  }
#pragma unroll
  for (int r = 0; r < 4; ++r) {
    float a0 = sc[0][r] * 0.125f, a1 = sc[1][r] * 0.125f;
    float a2 = sc[2][r] * 0.125f, a3 = sc[3][r] * 0.125f;
    float mx = fmaxf(fmaxf(a0, a1), fmaxf(a2, a3));
#pragma unroll
    for (int o = 1; o < 16; o <<= 1) mx = fmaxf(mx, __shfl_xor(mx, o));
    a0 = __expf(a0 - mx);
    a1 = __expf(a1 - mx);
    a2 = __expf(a2 - mx);
    a3 = __expf(a3 - mx);
    float se = a0 + a1 + a2 + a3;
#pragma unroll
    for (int o = 1; o < 16; o <<= 1) se += __shfl_xor(se, o);
    float inv = 1.f / se;
    int prow = wave * 16 + fg * 4 + r;
    Ps[prow][0 + fr] = f2bf(a0 * inv);
    Ps[prow][16 + fr] = f2bf(a1 * inv);
    Ps[prow][32 + fr] = f2bf(a2 * inv);
    Ps[prow][48 + fr] = f2bf(a3 * inv);
  }
  f32x4 oc[4] = {};
  bf16x8 ap0 = *(const bf16x8*)&Ps[wave * 16 + fr][fg * 8];
  bf16x8 ap1 = *(const bf16x8*)&Ps[wave * 16 + fr][32 + fg * 8];
#pragma unroll
  for (int nt = 0; nt < 4; ++nt) {
    bf16x8 b0 = *(const bf16x8*)&VT[nt * 16 + fr][fg * 8];
    bf16x8 b1 = *(const bf16x8*)&VT[nt * 16 + fr][32 + fg * 8];
    oc[nt] = __builtin_amdgcn_mfma_f32_16x16x32_bf16(ap0, b0, oc[nt], 0, 0, 0);
    oc[nt] = __builtin_amdgcn_mfma_f32_16x16x32_bf16(ap1, b1, oc[nt], 0, 0, 0);
  }
#pragma unroll
  for (int nt = 0; nt < 4; ++nt) {
#pragma unroll
    for (int r = 0; r < 4; ++r) {
      int q = wave * 16 + fg * 4 + r;
      int d = nt * 16 + fr;
      O[(size_t)(q * 16 + b) * 512 + h * 64 + d] = f2bf(oc[nt][r]);
    }
  }
}

// ---------------- batched bf16 MFMA GEMM (R7 LDS version) -------------------
struct GemmJob {
  const unsigned short* X;
  const unsigned short* W;
  const float* bias;
  const float* resid;
  float* Y;
  unsigned short* Ybf;
  float scale;
  int relu;
};
struct GemmBatch {
  GemmJob j[5];
};

__global__ __launch_bounds__(256) void gemm_bf16(GemmBatch gb, int M, int N,
                                                 int K) {
  const GemmJob jb = gb.j[blockIdx.z];
  __shared__ unsigned short As[64][72];  // 144B stride = 9x16B aligned
  __shared__ unsigned short Bs[64][72];
  const int t = threadIdx.x;
  const int lane = t & 63;
  const int wave = t >> 6;
  const int wr = wave >> 1;
  const int wc = wave & 1;
  const int bm = blockIdx.y * 64;
  const int bn = blockIdx.x * 64;

  f32x4 acc[2][2] = {};
  const unsigned short* Xp = jb.X + (size_t)bm * K;
  const unsigned short* Wp = jb.W + (size_t)bn * K;

  const int c0 = t, c1 = t + 256;
  const int r0 = c0 >> 3, o0 = (c0 & 7) * 8;
  const int r1 = c1 >> 3, o1 = (c1 & 7) * 8;

  u16x8 xa0 = *(const u16x8*)&Xp[(size_t)r0 * K + o0];
  u16x8 xa1 = *(const u16x8*)&Xp[(size_t)r1 * K + o1];
  u16x8 wa0 = *(const u16x8*)&Wp[(size_t)r0 * K + o0];
  u16x8 wa1 = *(const u16x8*)&Wp[(size_t)r1 * K + o1];

  for (int k0 = 0; k0 < K; k0 += 64) {
    *(u16x8*)&As[r0][o0] = xa0;
    *(u16x8*)&As[r1][o1] = xa1;
    *(u16x8*)&Bs[r0][o0] = wa0;
    *(u16x8*)&Bs[r1][o1] = wa1;
    __syncthreads();
    if (k0 + 64 < K) {
      int kn = k0 + 64;
      xa0 = *(const u16x8*)&Xp[(size_t)r0 * K + kn + o0];
      xa1 = *(const u16x8*)&Xp[(size_t)r1 * K + kn + o1];
      wa0 = *(const u16x8*)&Wp[(size_t)r0 * K + kn + o0];
      wa1 = *(const u16x8*)&Wp[(size_t)r1 * K + kn + o1];
    }
#pragma unroll
    for (int ks = 0; ks < 2; ++ks) {
      int kk = ks * 32 + (lane >> 4) * 8;
      int fr = lane & 15;
      bf16x8 a0 = *(const bf16x8*)&As[wr * 32 + fr][kk];
      bf16x8 a1 = *(const bf16x8*)&As[wr * 32 + 16 + fr][kk];
      bf16x8 b0 = *(const bf16x8*)&Bs[wc * 32 + fr][kk];
      bf16x8 b1 = *(const bf16x8*)&Bs[wc * 32 + 16 + fr][kk];
      acc[0][0] = __builtin_amdgcn_mfma_f32_16x16x32_bf16(a0, b0, acc[0][0], 0, 0, 0);
      acc[0][1] = __builtin_amdgcn_mfma_f32_16x16x32_bf16(a0, b1, acc[0][1], 0, 0, 0);
      acc[1][0] = __builtin_amdgcn_mfma_f32_16x16x32_bf16(a1, b0, acc[1][0], 0, 0, 0);
      acc[1][1] = __builtin_amdgcn_mfma_f32_16x16x32_bf16(a1, b1, acc[1][1], 0, 0, 0);
    }
    __syncthreads();
  }
#pragma unroll
  for (int mt = 0; mt < 2; ++mt) {
#pragma unroll
    for (int nt = 0; nt < 2; ++nt) {
      int col = bn + wc * 32 + nt * 16 + (lane & 15);
      int rowb = bm + wr * 32 + mt * 16 + (lane >> 4) * 4;
      float bia = jb.bias ? jb.bias[col] : 0.f;
#pragma unroll
      for (int r = 0; r < 4; ++r) {
        float v = (acc[mt][nt][r] + bia) * jb.scale;
        if (jb.relu) v = fmaxf(v, 0.f);
        if (jb.resid) v += jb.resid[(size_t)(rowb + r) * N + col];
        size_t idx = (size_t)(rowb + r) * N + col;
        if (jb.Y) jb.Y[idx] = v;
        if (jb.Ybf) jb.Ybf[idx] = f2bf(v);
      }
    }
  }
}

extern "C" void kernel_launch(void* const* d_in, const int* in_sizes, int n_in,
                              void* d_out, int out_size, void* d_ws,
                              size_t ws_size, hipStream_t stream) {
  const float* enc = (const float*)d_in[0];
  const float* dec = (const float*)d_in[1];
  const float* ec_Wi = (const float*)d_in[2];
  const float* ec_bi = (const float*)d_in[3];
  const float* ec_Wo = (const float*)d_in[4];
  const float* ec_bo = (const float*)d_in[5];
  const float* dc_Wi = (const float*)d_in[6];
  const float* dc_bi = (const float*)d_in[7];
  const float* dc_Wo = (const float*)d_in[8];
  const float* dc_bo = (const float*)d_in[9];
  const float* es_Wi = (const float*)d_in[10];
  const float* es_bi = (const float*)d_in[11];
  const float* es_Wo = (const float*)d_in[12];
  const float* es_bo = (const float*)d_in[13];
  const float* ds_Wi = (const float*)d_in[14];
  const float* ds_bi = (const float*)d_in[15];
  const float* ds_Wo = (const float*)d_in[16];
  const float* ds_bo = (const float*)d_in[17];
  const float* eff_W1 = (const float*)d_in[18];
  const float* eff_b1 = (const float*)d_in[19];
  const float* eff_W2 = (const float*)d_in[20];
  const float* eff_b2 = (const float*)d_in[21];
  const float* dff_W1 = (const float*)d_in[22];
  const float* dff_b1 = (const float*)d_in[23];
  const float* dff_W2 = (const float*)d_in[24];
  const float* dff_b2 = (const float*)d_in[25];
  const float* n_ec_g = (const float*)d_in[26];
  const float* n_ec_b = (const float*)d_in[27];
  const float* n_es_g = (const float*)d_in[28];
  const float* n_es_b = (const float*)d_in[29];
  const float* n_ef_g = (const float*)d_in[30];
  const float* n_ef_b = (const float*)d_in[31];
  const float* n_dci_g = (const float*)d_in[34];
  const float* n_dci_b = (const float*)d_in[35];
  const float* n_ds_g = (const float*)d_in[36];
  const float* n_ds_b = (const float*)d_in[37];
  const float* n_df_g = (const float*)d_in[38];
  const float* n_df_b = (const float*)d_in[39];
  const float* pW = (const float*)d_in[40];
  const float* pWb = (const float*)d_in[41];
  const float* pv = (const float*)d_in[42];
  const float* pb = (const float*)d_in[43];

  float* ws = (float*)d_ws;
  const size_t U = 524288;  // 1024*512 elements
  float* Ed = ws + 3 * U;
  float* tb = ws + 4 * U;
  float* Et = ws + 7 * U;
  float* enc1 = ws + 8 * U;
  float* dec1 = ws + 9 * U;
  float* enc2 = ws + 10 * U;
  float* dec2 = ws + 11 * U;
  float* sm = ws + 12 * U;
  float* md = sm;
  float* q2d = sm + 1024;
  float* mt = sm + 2048;
  float* q2t = sm + 3072;
  float* u_k = sm + 4096;
  float* u_v = sm + 4608;
  float* c_k = sm + 5120;
  float* c_v = sm + 5632;
  float* mArr = sm + 6144;           // b-major [b][j][i], 65536
  float* rArr = sm + 6144 + 65536;
  unsigned short* ub0 = (unsigned short*)ws;
  unsigned short* Qe_b = ub0 + 0 * U;
  unsigned short* Kd_b = ub0 + 1 * U;
  unsigned short* Vd_b = ub0 + 2 * U;
  unsigned short* Kt_b = ub0 + 3 * U;
  unsigned short* Vt_b = ub0 + 4 * U;
  unsigned short* ub = (unsigned short*)(ws + 12 * U + 137216);
  const int W262 = 262144, W786 = 786432, W1M = 1048576;
  unsigned short* w_dcWv = ub;
  unsigned short* w_ecWq = w_dcWv + W262;
  unsigned short* w_ecWkg = w_ecWq + W262;
  unsigned short* w_ecWvg = w_ecWkg + W262;
  unsigned short* w_pW = w_ecWvg + W262;
  unsigned short* w_dcWo = w_pW + W262;
  unsigned short* w_ecWo = w_dcWo + W262;
  unsigned short* w_esWi = w_ecWo + W262;
  unsigned short* w_dsWi = w_esWi + W786;
  unsigned short* w_esWo = w_dsWi + W786;
  unsigned short* w_dsWo = w_esWo + W262;
  unsigned short* w_effW1 = w_dsWo + W262;
  unsigned short* w_dffW1 = w_effW1 + W1M;
  unsigned short* w_effW2 = w_dffW1 + W1M;
  unsigned short* w_dffW2 = w_effW2 + W1M;
  unsigned short* actb = w_dffW2 + W1M;
  unsigned short* f_n_b = actb;
  unsigned short* V1_b = actb + U;
  unsigned short* dec_b = actb + 2 * U;
  unsigned short* tb_b = actb + 3 * U;
  unsigned short* Oec_b = actb + 4 * U;
  unsigned short* nbE = f_n_b;
  unsigned short* nbD = V1_b;
  unsigned short* OaE = dec_b;
  unsigned short* OaD = tb_b;
  unsigned short* QKVe_b = (unsigned short*)(ws + 0 * U);
  unsigned short* QKVd_b = (unsigned short*)(ws + 2 * U);
  unsigned short* He_b = (unsigned short*)(ws + 0 * U);
  unsigned short* Hd_b = (unsigned short*)(ws + 2 * U);

  const float* dc_Wv = dc_Wi + 1024 * 512;
  const float* dc_bv = dc_bi + 1024;
  const float* ec_Wq = ec_Wi;
  const float* ec_bq = ec_bi;
  const float* ec_Wk = ec_Wi + 512 * 512;
  const float* ec_bk = ec_bi + 512;
  const float* ec_Wv = ec_Wi + 1024 * 512;
  const float* ec_bv = ec_bi + 1024;

  // 0. weight casts
  {
    CastBatch cb{};
    cb.j[0] = {dc_Wv, w_dcWv, W262, nullptr};
    cb.j[1] = {ec_Wq, w_ecWq, W262, nullptr};
    cb.j[2] = {ec_Wk, w_ecWkg, W262, n_dci_g};
    cb.j[3] = {ec_Wv, w_ecWvg, W262, n_dci_g};
    cb.j[4] = {pW, w_pW, W262, nullptr};
    cb.j[5] = {dc_Wo, w_dcWo, W262, nullptr};
    cb.j[6] = {ec_Wo, w_ecWo, W262, nullptr};
    cb.j[7] = {es_Wi, w_esWi, W786, nullptr};
    cb.j[8] = {ds_Wi, w_dsWi, W786, nullptr};
    cb.j[9] = {es_Wo, w_esWo, W262, nullptr};
    cb.j[10] = {ds_Wo, w_dsWo, W262, nullptr};
    cb.j[11] = {eff_W1, w_effW1, W1M, nullptr};
    cb.j[12] = {dff_W1, w_dffW1, W1M, nullptr};
    cb.j[13] = {eff_W2, w_effW2, W1M, nullptr};
    cb.j[14] = {dff_W2, w_dffW2, W1M, nullptr};
    cast_w<<<dim3(32, 15), 256, 0, stream>>>(cb);
  }
  // 1+2. LN(enc)->bf16 fused with dec stats+cast
  ln_stats_kernel<<<2048, 256, 0, stream>>>(enc, n_ec_g, n_ec_b, f_n_b, dec,
                                            md, q2d, dec_b);
  // 3. u/c vectors
  uvec_kernel<<<128, 256, 0, stream>>>(ec_Wk, ec_Wv, ec_bk, ec_bv, n_dci_g,
                                       n_dci_b, u_k, u_v, c_k, c_v);
  // 4. batch A
  {
    GemmBatch gb{};
    gb.j[0] = {f_n_b, w_dcWv, dc_bv, nullptr, nullptr, V1_b, 1.f, 0};
    gb.j[1] = {f_n_b, w_ecWq, ec_bq, nullptr, nullptr, Qe_b, 0.125f, 0};
    gb.j[2] = {dec_b, w_ecWkg, nullptr, nullptr, nullptr, Kd_b, 1.f, 0};
    gb.j[3] = {dec_b, w_ecWvg, nullptr, nullptr, nullptr, Vd_b, 1.f, 0};
    gb.j[4] = {dec_b, w_pW, pWb, nullptr, Ed, nullptr, 1.f, 0};
    gemm_bf16<<<dim3(8, 16, 5), 256, 0, stream>>>(gb, 1024, 512, 512);
  }
  // 5. t = V1 @ dc_Wo^T + dc_bo  (fp32 + bf16)
  {
    GemmBatch gb{};
    gb.j[0] = {V1_b, w_dcWo, dc_bo, nullptr, tb, tb_b, 1.f, 0};
    gemm_bf16<<<dim3(8, 16, 1), 256, 0, stream>>>(gb, 1024, 512, 512);
  }
  // 6. t row stats
  stats_kernel<<<1024, 256, 0, stream>>>(tb, mt, q2t, nullptr);
  // 7. batch B
  {
    GemmBatch gb{};
    gb.j[0] = {tb_b, w_ecWkg, nullptr, nullptr, nullptr, Kt_b, 1.f, 0};
    gb.j[1] = {tb_b, w_ecWvg, nullptr, nullptr, nullptr, Vt_b, 1.f, 0};
    gb.j[2] = {tb_b, w_pW, pb, nullptr, Et, nullptr, 1.f, 0};
    gemm_bf16<<<dim3(8, 16, 3), 256, 0, stream>>>(gb, 1024, 512, 512);
  }
  // 8. per-(j,i,b) LN stats (bf16 inputs)
  mr_kernel<<<16384, 256, 0, stream>>>(dec_b, tb_b, md, q2d, mt, q2t, mArr,
                                       rArr);
  // 9. ec cross-attention (MFMA)
  ec_attn<<<128, 256, 0, stream>>>(Qe_b, Kd_b, Kt_b, Vd_b, Vt_b, u_k, u_v, c_k,
                                   c_v, mArr, rArr, Oec_b);
  // 10. pooling -> dec1
  pool_kernel<<<dim3(64, 16), 256, 0, stream>>>(Ed, Et, pv, dec, tb_b, dec1);
  // 11. enc1 = enc + O_ec @ ec_Wo^T + ec_bo
  {
    GemmBatch gb{};
    gb.j[0] = {Oec_b, w_ecWo, ec_bo, enc, enc1, nullptr, 1.f, 0};
    gemm_bf16<<<dim3(8, 16, 1), 256, 0, stream>>>(gb, 1024, 512, 512);
  }
  // 12. pre-norm for self-attention
  ln2_kernel<<<2048, 256, 0, stream>>>(enc1, n_es_g, n_es_b, nbE, dec1, n_ds_g,
                                       n_ds_b, nbD);
  // 13. QKV projections
  {
    GemmBatch gb{};
    gb.j[0] = {nbE, w_esWi, es_bi, nullptr, nullptr, QKVe_b, 1.f, 0};
    gb.j[1] = {nbD, w_dsWi, ds_bi, nullptr, nullptr, QKVd_b, 1.f, 0};
    gemm_bf16<<<dim3(24, 16, 2), 256, 0, stream>>>(gb, 1024, 1536, 512);
  }
  // 14. self-attention cores (MFMA)
  self_attn<<<dim3(128, 2), 256, 0, stream>>>(QKVe_b, OaE, QKVd_b, OaD);
  // 15. output proj + residual
  {
    GemmBatch gb{};
    gb.j[0] = {OaE, w_esWo, es_bo, enc1, enc2, nullptr, 1.f, 0};
    gb.j[1] = {OaD, w_dsWo, ds_bo, dec1, dec2, nullptr, 1.f, 0};
    gemm_bf16<<<dim3(8, 16, 2), 256, 0, stream>>>(gb, 1024, 512, 512);
  }
  // 16. pre-norm for FFN
  ln2_kernel<<<2048, 256, 0, stream>>>(enc2, n_ef_g, n_ef_b, nbE, dec2, n_df_g,
                                       n_df_b, nbD);
  // 17. FFN layer 1 (relu)
  {
    GemmBatch gb{};
    gb.j[0] = {nbE, w_effW1, eff_b1, nullptr, nullptr, He_b, 1.f, 1};
    gb.j[1] = {nbD, w_dffW1, dff_b1, nullptr, nullptr, Hd_b, 1.f, 1};
    gemm_bf16<<<dim3(32, 16, 2), 256, 0, stream>>>(gb, 1024, 2048, 512);
  }
  // 18. FFN layer 2 + residual -> outputs
  float* out = (float*)d_out;
  {
    GemmBatch gb{};
    gb.j[0] = {He_b, w_effW2, eff_b2, enc2, out, nullptr, 1.f, 0};
    gb.j[1] = {Hd_b, w_dffW2, dff_b2, dec2, out + U, nullptr, 1.f, 0};
    gemm_bf16<<<dim3(8, 16, 2), 256, 0, stream>>>(gb, 1024, 512, 2048);
  }
}